// Round 8
// baseline (545.436 us; speedup 1.0000x reference)
//
#include <hip/hip_runtime.h>
#include <hip/hip_bf16.h>
#include <math.h>

// Problem constants (fixed by setup_inputs)
#define BB 4
#define NN 16384
#define SS 4096
#define D1 128
#define D2 256
#define C1 256   // mlp[0]
#define C2 128   // mlp[1]
#define MTOT (BB*NN)   // 65536

// knn decomposition
#define QPT 4              // queries per thread (ILP + LDS amortization)
#define SCH 512            // candidates per chunk (8KB LDS)
#define NCH (SS/SCH)       // 8 chunks

typedef _Float16 f16x8 __attribute__((ext_vector_type(8)));
typedef float f32x4  __attribute__((ext_vector_type(4)));

#define LPAD 40            // LDS row stride in fp16 elems (80B, 16B-aligned)

// ---------------------------------------------------------------------------
// Pack xyz2 into float4 {x, y, z, ||p||^2} (exact reference association).
// ---------------------------------------------------------------------------
__global__ __launch_bounds__(256) void pack_kernel(
    const float* __restrict__ xyz2, float4* __restrict__ packed)
{
#pragma clang fp contract(off)
    int s = blockIdx.x * 256 + threadIdx.x;
    float px = xyz2[s*3+0], py = xyz2[s*3+1], pz = xyz2[s*3+2];
    float pp = (px*px + py*py) + pz*pz;
    packed[s] = make_float4(px, py, pz, pp);
}

// ---------------------------------------------------------------------------
// Convert W1, W2 to fp16 (RNE) once.
// ---------------------------------------------------------------------------
__global__ __launch_bounds__(256) void wcvt_kernel(
    const float* __restrict__ W1, const float* __restrict__ W2,
    _Float16* __restrict__ W1c, _Float16* __restrict__ W2c)
{
    int i = blockIdx.x * 256 + threadIdx.x;
    if (i < C1 * (D1 + D2)) W1c[i] = (_Float16)W1[i];
    if (i < C2 * C1)        W2c[i] = (_Float16)W2[i];
}

// ---------------------------------------------------------------------------
// 3-NN pass 1: branch-free per-chunk top-3 with EXACT fp32 selection.
// HARD CONSTRAINT (learned R7): selection is discontinuous in the gathered
// features -> distance formula must match the reference bit-for-bit
// (contract off, same association) and comparisons must be exact fp32.
// Distance triple via min/med3; index chain via cndmask from pre-update
// compares; strict '<' keeps earliest candidate on ties (lax.top_k stable).
// ---------------------------------------------------------------------------
__global__ __launch_bounds__(256) void knn3_partial_kernel(
    const float* __restrict__ xyz1, const float4* __restrict__ packed,
    float* __restrict__ pdist, int* __restrict__ pidx)
{
#pragma clang fp contract(off)
    __shared__ float4 pk[SCH];                       // 8 KB

    const int qblocks = NN / (256 * QPT);            // 16
    const int b  = blockIdx.x / (qblocks * NCH);
    const int r  = blockIdx.x % (qblocks * NCH);
    const int qc = r / NCH;
    const int sc = r % NCH;

    const float4* src = packed + (size_t)b * SS + sc * SCH;
    for (int i = threadIdx.x; i < SCH; i += 256) pk[i] = src[i];
    __syncthreads();

    float qx[QPT], qy[QPT], qz[QPT], qq[QPT];
    float e0[QPT], e1[QPT], e2[QPT];
    int   j0[QPT], j1[QPT], j2[QPT];
#pragma unroll
    for (int q = 0; q < QPT; ++q) {
        int n = qc * (256 * QPT) + q * 256 + threadIdx.x;
        size_t m = (size_t)b * NN + n;
        qx[q] = xyz1[m*3+0]; qy[q] = xyz1[m*3+1]; qz[q] = xyz1[m*3+2];
        qq[q] = (qx[q]*qx[q] + qy[q]*qy[q]) + qz[q]*qz[q];
        e0[q] = 3.4e38f; e1[q] = 3.4e38f; e2[q] = 3.4e38f;
        j0[q] = 0; j1[q] = 0; j2[q] = 0;
    }

#pragma unroll 4
    for (int s = 0; s < SCH; ++s) {
        float4 p = pk[s];
#pragma unroll
        for (int q = 0; q < QPT; ++q) {
            float cr = (qx[q]*p.x + qy[q]*p.y) + qz[q]*p.z;
            float d = (qq[q] - 2.0f*cr) + p.w;
            d = fmaxf(d, 0.0f);
            bool c0 = d < e0[q], c1 = d < e1[q], c2 = d < e2[q];
            j2[q] = c1 ? j1[q] : (c2 ? s : j2[q]);
            j1[q] = c0 ? j0[q] : (c1 ? s : j1[q]);
            j0[q] = c0 ? s : j0[q];
            e2[q] = __builtin_amdgcn_fmed3f(e1[q], d, e2[q]);
            e1[q] = __builtin_amdgcn_fmed3f(e0[q], d, e1[q]);
            e0[q] = fminf(e0[q], d);
        }
    }

#pragma unroll
    for (int q = 0; q < QPT; ++q) {
        int n = qc * (256 * QPT) + q * 256 + threadIdx.x;
        size_t m = (size_t)b * NN + n;
        size_t base = (m * NCH + sc) * 3;
        pdist[base+0] = e0[q]; pdist[base+1] = e1[q]; pdist[base+2] = e2[q];
        pidx [base+0] = sc*SCH + j0[q];
        pidx [base+1] = sc*SCH + j1[q];
        pidx [base+2] = sc*SCH + j2[q];
    }
}

// ---------------------------------------------------------------------------
// 3-NN pass 2: merge chunk triples (ascending chunk order, strict '<').
// ---------------------------------------------------------------------------
__global__ __launch_bounds__(256) void knn3_merge_kernel(
    const float* __restrict__ pdist, const int* __restrict__ pidx,
    int* __restrict__ idx_out, float* __restrict__ w_out)
{
#pragma clang fp contract(off)
    int m = blockIdx.x * 256 + threadIdx.x;
    int b = m / NN;
    size_t base = (size_t)m * NCH * 3;
    float d0 = pdist[base+0], d1 = pdist[base+1], d2 = pdist[base+2];
    int   i0 = pidx [base+0], i1 = pidx [base+1], i2 = pidx [base+2];
#pragma unroll
    for (int c = 1; c < NCH; ++c) {
#pragma unroll
        for (int j = 0; j < 3; ++j) {
            float d = pdist[base + c*3 + j];
            int   s = pidx [base + c*3 + j];
            bool c0 = d < d0, c1 = d < d1, c2 = d < d2;
            d2 = c1 ? d1 : (c2 ? d : d2);  i2 = c1 ? i1 : (c2 ? s : i2);
            d1 = c0 ? d0 : (c1 ? d : d1);  i1 = c0 ? i0 : (c1 ? s : i1);
            d0 = c0 ? d : d0;              i0 = c0 ? s : i0;
        }
    }
    float r0 = 1.0f / (d0 + 1e-8f);
    float r1 = 1.0f / (d1 + 1e-8f);
    float r2 = 1.0f / (d2 + 1e-8f);
    float inv = 1.0f / ((r0 + r1) + r2);
    idx_out[m*3+0] = b * SS + i0;
    idx_out[m*3+1] = b * SS + i1;
    idx_out[m*3+2] = b * SS + i2;
    w_out[m*3+0] = r0 * inv;
    w_out[m*3+1] = r1 * inv;
    w_out[m*3+2] = r2 * inv;
}

// ---------------------------------------------------------------------------
// fp16 MFMA GEMM with register double-buffered staging:
// prefetch chunk k+1's A/B into regs while MFMAing chunk k, so the global
// load latency overlaps compute instead of draining at the barrier.
// Tile 64(M) x 128(N), 4 waves of 32x64, k-chunk 32 (16x16x32 f16 MFMA).
// Optional fused: BN+ReLU on A (register stage); interp gather; BN stats.
// ---------------------------------------------------------------------------
template<int K, bool BN_A, bool FUSE_INTERP, bool FUSE_STATS>
__global__ __launch_bounds__(256, 4) void gemm_mfma_kernel(
    const float* __restrict__ A, int lda,
    const _Float16* __restrict__ W, int ldw,
    float* __restrict__ C, int ldc,
    const float* __restrict__ bias,
    const float* __restrict__ scaleA, const float* __restrict__ shiftA,
    const float* __restrict__ P2, const int* __restrict__ idx3, const float* __restrict__ w3,
    float* __restrict__ sumO, float* __restrict__ sqO)
{
    __shared__ _Float16 Ash[64 * LPAD];     // 5 KB
    __shared__ _Float16 Bsh[128 * LPAD];    // 10 KB

    const int tid = threadIdx.x;
    const int m0 = blockIdx.x * 64;
    const int n0 = blockIdx.y * 128;
    const int wave = tid >> 6, lane = tid & 63;
    const int ln = lane & 15, q4 = lane >> 4;
    const int wm = wave & 1, wn = wave >> 1;

    const int ar = tid >> 2, ak = (tid & 3) * 8;   // A staging: 64 rows x 32k
    const int br = tid >> 1, bk = (tid & 1) * 16;  // B staging: 128 rows x 32k

    f32x4 acc[2][4] = {};

    float  avA[8];
    f16x8  bvA[2];
    {   // prologue prefetch k0 = 0
        const float* ap = A + (size_t)(m0 + ar) * lda + ak;
        *(float4*)&avA[0] = *(const float4*)ap;
        *(float4*)&avA[4] = *(const float4*)(ap + 4);
        const _Float16* bp = W + (size_t)(n0 + br) * ldw + bk;
        bvA[0] = *(const f16x8*)bp;
        bvA[1] = *(const f16x8*)(bp + 8);
    }

    for (int k0 = 0; k0 < K; k0 += 32) {
        if (k0) __syncthreads();               // prev-iter LDS consumers done

        // ---- transform + store staged regs to LDS ----
        {
            float av[8];
#pragma unroll
            for (int i = 0; i < 8; ++i) av[i] = avA[i];
            if (BN_A) {
#pragma unroll
                for (int i = 0; i < 8; ++i) {
                    float sc = scaleA[k0 + ak + i];
                    float sh = shiftA[k0 + ak + i];
                    av[i] = fmaxf(av[i] * sc + sh, 0.0f);
                }
            }
            f16x8 vh;
#pragma unroll
            for (int i = 0; i < 8; ++i) vh[i] = (_Float16)av[i];
            *(f16x8*)&Ash[ar * LPAD + ak] = vh;
            *(f16x8*)&Bsh[br * LPAD + bk]     = bvA[0];
            *(f16x8*)&Bsh[br * LPAD + bk + 8] = bvA[1];
        }
        __syncthreads();

        // ---- issue next chunk's global loads (overlap with MFMA below) ----
        if (k0 + 32 < K) {
            const float* ap = A + (size_t)(m0 + ar) * lda + (k0 + 32) + ak;
            *(float4*)&avA[0] = *(const float4*)ap;
            *(float4*)&avA[4] = *(const float4*)(ap + 4);
            const _Float16* bp = W + (size_t)(n0 + br) * ldw + (k0 + 32) + bk;
            bvA[0] = *(const f16x8*)bp;
            bvA[1] = *(const f16x8*)(bp + 8);
        }

        // ---- fragments + MFMA ----
        f16x8 af[2];
#pragma unroll
        for (int mi = 0; mi < 2; ++mi) {
            int arow = wm * 32 + mi * 16 + ln;
            af[mi] = *(const f16x8*)&Ash[arow * LPAD + q4 * 8];
        }
        f16x8 bf[4];
#pragma unroll
        for (int ni = 0; ni < 4; ++ni) {
            int brow = wn * 64 + ni * 16 + ln;
            bf[ni] = *(const f16x8*)&Bsh[brow * LPAD + q4 * 8];
        }
#pragma unroll
        for (int mi = 0; mi < 2; ++mi)
#pragma unroll
            for (int ni = 0; ni < 4; ++ni)
                acc[mi][ni] = __builtin_amdgcn_mfma_f32_16x16x32_f16(af[mi], bf[ni], acc[mi][ni], 0, 0, 0);
    }

    // ---- epilogue ----  C/D layout: col = ln, row = q4*4 + r  (m89/m91)
    if (FUSE_INTERP) {
#pragma unroll
        for (int mi = 0; mi < 2; ++mi) {
#pragma unroll
            for (int r = 0; r < 4; ++r) {
                int row_g = m0 + wm * 32 + mi * 16 + q4 * 4 + r;
                const int*   ip = idx3 + (size_t)row_g * 3;
                const float* wp = w3   + (size_t)row_g * 3;
                int   ia = ip[0], ib = ip[1], ic = ip[2];
                float wa = wp[0], wb = wp[1], wc = wp[2];
#pragma unroll
                for (int ni = 0; ni < 4; ++ni) {
                    int col = n0 + wn * 64 + ni * 16 + ln;
                    acc[mi][ni][r] += wa * P2[(size_t)ia * C1 + col]
                                    + wb * P2[(size_t)ib * C1 + col]
                                    + wc * P2[(size_t)ic * C1 + col];
                }
            }
        }
    }

#pragma unroll
    for (int ni = 0; ni < 4; ++ni) {
        int col = n0 + wn * 64 + ni * 16 + ln;
        float vb = bias ? bias[col] : 0.0f;
        float s = 0.0f, s2 = 0.0f;
#pragma unroll
        for (int mi = 0; mi < 2; ++mi) {
#pragma unroll
            for (int r = 0; r < 4; ++r) {
                int row_g = m0 + wm * 32 + mi * 16 + q4 * 4 + r;
                float v = acc[mi][ni][r] + vb;
                C[(size_t)row_g * ldc + col] = v;
                s += v; s2 += v * v;
            }
        }
        if (FUSE_STATS) {
            s  += __shfl_xor(s, 16);  s  += __shfl_xor(s, 32);
            s2 += __shfl_xor(s2, 16); s2 += __shfl_xor(s2, 32);
            if (q4 == 0) {
                atomicAdd(&sumO[col], s);
                atomicAdd(&sqO[col], s2);
            }
        }
    }
}

// ---------------------------------------------------------------------------
__global__ void finalize_kernel(
    const float* __restrict__ sum, const float* __restrict__ sumsq,
    const float* __restrict__ g, const float* __restrict__ beta,
    int M, int C, float* __restrict__ scale, float* __restrict__ shift)
{
    int c = threadIdx.x;
    if (c >= C) return;
    float invM = 1.0f / (float)M;
    float mean = sum[c] * invM;
    float var = fmaxf(sumsq[c] * invM - mean * mean, 0.0f);
    float rstd = 1.0f / sqrtf(var + 1e-5f);
    float sc = g[c] * rstd;
    scale[c] = sc;
    shift[c] = beta[c] - mean * sc;
}

__global__ __launch_bounds__(256) void bnrelu_kernel(
    float* __restrict__ X, int total, int C,
    const float* __restrict__ scale, const float* __restrict__ shift)
{
    int i = blockIdx.x * 256 + threadIdx.x;
    if (i >= total) return;
    int c = i & (C - 1);
    X[i] = fmaxf(X[i] * scale[c] + shift[c], 0.0f);
}

// ---------------------------------------------------------------------------
extern "C" void kernel_launch(void* const* d_in, const int* in_sizes, int n_in,
                              void* d_out, int out_size, void* d_ws, size_t ws_size,
                              hipStream_t stream) {
    const float* xyz1    = (const float*)d_in[0];
    const float* xyz2    = (const float*)d_in[1];
    const float* points1 = (const float*)d_in[2];
    const float* points2 = (const float*)d_in[3];
    const float* W1      = (const float*)d_in[4];
    const float* b1      = (const float*)d_in[5];
    const float* g1      = (const float*)d_in[6];
    const float* beta1   = (const float*)d_in[7];
    const float* W2      = (const float*)d_in[8];
    const float* b2      = (const float*)d_in[9];
    const float* g2      = (const float*)d_in[10];
    const float* beta2   = (const float*)d_in[11];
    float* out = (float*)d_out;

    // ws layout (16B-aligned chunks)
    char* ws = (char*)d_ws;
    int*   idx = (int*)ws;                                 // MTOT*3
    float* w   = (float*)(ws + (size_t)MTOT*3*4);          // MTOT*3
    float* P2  = (float*)(ws + (size_t)MTOT*6*4);          // B*S*C1
    float* y1  = P2 + (size_t)BB*SS*C1;                    // MTOT*C1
    float* stats = y1 + (size_t)MTOT*C1;                   // 2048 floats
    float* sum1 = stats;            // 256
    float* sq1  = stats + 256;      // 256
    float* sum2 = stats + 512;      // 128
    float* sq2  = stats + 640;      // 128
    float* scale1 = stats + 768;    // 256
    float* shift1 = stats + 1024;   // 256
    float* scale2 = stats + 1280;   // 128
    float* shift2 = stats + 1408;   // 128
    float4* packed = (float4*)(stats + 2048);              // B*S float4
    _Float16* W1c = (_Float16*)(packed + (size_t)BB*SS);
    _Float16* W2c = W1c + (size_t)C1*(D1+D2);

    // knn partials alias y1 (y1 written later in stream order)
    float* pdist = y1;                                     // MTOT*NCH*3
    int*   pidx  = (int*)(y1 + (size_t)MTOT*NCH*3);        // MTOT*NCH*3

    hipMemsetAsync(stats, 0, 768 * sizeof(float), stream);

    pack_kernel<<<(BB*SS)/256, 256, 0, stream>>>(xyz2, packed);
    wcvt_kernel<<<(C1*(D1+D2))/256, 256, 0, stream>>>(W1, W2, W1c, W2c);

    knn3_partial_kernel<<<BB * (NN/(256*QPT)) * NCH, 256, 0, stream>>>(
        xyz1, packed, pdist, pidx);
    knn3_merge_kernel<<<MTOT/256, 256, 0, stream>>>(pdist, pidx, idx, w);

    // P2 = points2 @ W1[:,128:]^T   [B*S x 256], K=256
    gemm_mfma_kernel<256, false, false, false><<<dim3((BB*SS)/64, C1/128), 256, 0, stream>>>(
        points2, D2, W1c + D1, D1 + D2, P2, C1,
        nullptr, nullptr, nullptr, nullptr, nullptr, nullptr, nullptr, nullptr);

    // y1 = points1 @ W1[:,:128]^T + b1 + interp;  fused BN1 stats
    gemm_mfma_kernel<128, false, true, true><<<dim3(MTOT/64, C1/128), 256, 0, stream>>>(
        points1, D1, W1c, D1 + D2, y1, C1,
        b1, nullptr, nullptr, P2, idx, w, sum1, sq1);

    finalize_kernel<<<1, 256, 0, stream>>>(sum1, sq1, g1, beta1, MTOT, C1, scale1, shift1);

    // out = relu(bn1(y1)) @ W2^T + b2;  fused BN2 stats
    gemm_mfma_kernel<256, true, false, true><<<dim3(MTOT/64, C2/128), 256, 0, stream>>>(
        y1, C1, W2c, C1, out, C2,
        b2, scale1, shift1, nullptr, nullptr, nullptr, sum2, sq2);

    finalize_kernel<<<1, 128, 0, stream>>>(sum2, sq2, g2, beta2, MTOT, C2, scale2, shift2);
    bnrelu_kernel<<<(MTOT*C2)/256, 256, 0, stream>>>(out, MTOT*C2, C2, scale2, shift2);
}

// Round 9
// 492.017 us; speedup vs baseline: 1.1086x; 1.1086x over previous
//
#include <hip/hip_runtime.h>
#include <hip/hip_bf16.h>
#include <math.h>

// Problem constants (fixed by setup_inputs)
#define BB 4
#define NN 16384
#define SS 4096
#define D1 128
#define D2 256
#define C1 256   // mlp[0]
#define C2 128   // mlp[1]
#define MTOT (BB*NN)   // 65536

// knn decomposition (R6 measured optimum: 174 us, VALUBusy ~107%)
#define QPT 2              // queries per thread
#define SCH 512            // candidates per chunk (8KB LDS)
#define NCH (SS/SCH)       // 8 chunks

typedef _Float16 f16x8 __attribute__((ext_vector_type(8)));
typedef float f32x4  __attribute__((ext_vector_type(4)));

#define LPAD 40            // LDS row stride in fp16 elems (80B, 16B-aligned)

// ---------------------------------------------------------------------------
// Pack xyz2 into float4 {x, y, z, ||p||^2} (exact reference association).
// ---------------------------------------------------------------------------
__global__ __launch_bounds__(256) void pack_kernel(
    const float* __restrict__ xyz2, float4* __restrict__ packed)
{
#pragma clang fp contract(off)
    int s = blockIdx.x * 256 + threadIdx.x;
    float px = xyz2[s*3+0], py = xyz2[s*3+1], pz = xyz2[s*3+2];
    float pp = (px*px + py*py) + pz*pz;
    packed[s] = make_float4(px, py, pz, pp);
}

// ---------------------------------------------------------------------------
// Convert W1, W2 to fp16 (RNE) once.
// ---------------------------------------------------------------------------
__global__ __launch_bounds__(256) void wcvt_kernel(
    const float* __restrict__ W1, const float* __restrict__ W2,
    _Float16* __restrict__ W1c, _Float16* __restrict__ W2c)
{
    int i = blockIdx.x * 256 + threadIdx.x;
    if (i < C1 * (D1 + D2)) W1c[i] = (_Float16)W1[i];
    if (i < C2 * C1)        W2c[i] = (_Float16)W2[i];
}

// ---------------------------------------------------------------------------
// 3-NN pass 1 (FROZEN = Round-6 config, measured 174us):
// exact fp32 distances (contract off, reference association), min/med3
// distance chain + cndmask index chain, strict '<' (stable like lax.top_k).
// HARD CONSTRAINT (R7): selection is discontinuous in gathered features ->
// never approximate the distance or the comparison.
// ---------------------------------------------------------------------------
__global__ __launch_bounds__(256) void knn3_partial_kernel(
    const float* __restrict__ xyz1, const float4* __restrict__ packed,
    float* __restrict__ pdist, int* __restrict__ pidx)
{
#pragma clang fp contract(off)
    __shared__ float4 pk[SCH];                       // 8 KB

    const int qblocks = NN / (256 * QPT);            // 32
    const int b  = blockIdx.x / (qblocks * NCH);
    const int r  = blockIdx.x % (qblocks * NCH);
    const int qc = r / NCH;
    const int sc = r % NCH;

    const float4* src = packed + (size_t)b * SS + sc * SCH;
    for (int i = threadIdx.x; i < SCH; i += 256) pk[i] = src[i];
    __syncthreads();

    float qx[QPT], qy[QPT], qz[QPT], qq[QPT];
    float e0[QPT], e1[QPT], e2[QPT];
    int   j0[QPT], j1[QPT], j2[QPT];
#pragma unroll
    for (int q = 0; q < QPT; ++q) {
        int n = qc * (256 * QPT) + q * 256 + threadIdx.x;
        size_t m = (size_t)b * NN + n;
        qx[q] = xyz1[m*3+0]; qy[q] = xyz1[m*3+1]; qz[q] = xyz1[m*3+2];
        qq[q] = (qx[q]*qx[q] + qy[q]*qy[q]) + qz[q]*qz[q];
        e0[q] = 3.4e38f; e1[q] = 3.4e38f; e2[q] = 3.4e38f;
        j0[q] = 0; j1[q] = 0; j2[q] = 0;
    }

#pragma unroll 4
    for (int s = 0; s < SCH; ++s) {
        float4 p = pk[s];
#pragma unroll
        for (int q = 0; q < QPT; ++q) {
            float cr = (qx[q]*p.x + qy[q]*p.y) + qz[q]*p.z;
            float d = (qq[q] - 2.0f*cr) + p.w;
            d = fmaxf(d, 0.0f);
            bool c0 = d < e0[q], c1 = d < e1[q], c2 = d < e2[q];
            j2[q] = c1 ? j1[q] : (c2 ? s : j2[q]);
            j1[q] = c0 ? j0[q] : (c1 ? s : j1[q]);
            j0[q] = c0 ? s : j0[q];
            e2[q] = __builtin_amdgcn_fmed3f(e1[q], d, e2[q]);
            e1[q] = __builtin_amdgcn_fmed3f(e0[q], d, e1[q]);
            e0[q] = fminf(e0[q], d);
        }
    }

#pragma unroll
    for (int q = 0; q < QPT; ++q) {
        int n = qc * (256 * QPT) + q * 256 + threadIdx.x;
        size_t m = (size_t)b * NN + n;
        size_t base = (m * NCH + sc) * 3;
        pdist[base+0] = e0[q]; pdist[base+1] = e1[q]; pdist[base+2] = e2[q];
        pidx [base+0] = sc*SCH + j0[q];
        pidx [base+1] = sc*SCH + j1[q];
        pidx [base+2] = sc*SCH + j2[q];
    }
}

// ---------------------------------------------------------------------------
// 3-NN pass 2: merge chunk triples (ascending chunk order, strict '<').
// ---------------------------------------------------------------------------
__global__ __launch_bounds__(256) void knn3_merge_kernel(
    const float* __restrict__ pdist, const int* __restrict__ pidx,
    int* __restrict__ idx_out, float* __restrict__ w_out)
{
#pragma clang fp contract(off)
    int m = blockIdx.x * 256 + threadIdx.x;
    int b = m / NN;
    size_t base = (size_t)m * NCH * 3;
    float d0 = pdist[base+0], d1 = pdist[base+1], d2 = pdist[base+2];
    int   i0 = pidx [base+0], i1 = pidx [base+1], i2 = pidx [base+2];
#pragma unroll
    for (int c = 1; c < NCH; ++c) {
#pragma unroll
        for (int j = 0; j < 3; ++j) {
            float d = pdist[base + c*3 + j];
            int   s = pidx [base + c*3 + j];
            bool c0 = d < d0, c1 = d < d1, c2 = d < d2;
            d2 = c1 ? d1 : (c2 ? d : d2);  i2 = c1 ? i1 : (c2 ? s : i2);
            d1 = c0 ? d0 : (c1 ? d : d1);  i1 = c0 ? i0 : (c1 ? s : i1);
            d0 = c0 ? d : d0;              i0 = c0 ? s : i0;
        }
    }
    float r0 = 1.0f / (d0 + 1e-8f);
    float r1 = 1.0f / (d1 + 1e-8f);
    float r2 = 1.0f / (d2 + 1e-8f);
    float inv = 1.0f / ((r0 + r1) + r2);
    idx_out[m*3+0] = b * SS + i0;
    idx_out[m*3+1] = b * SS + i1;
    idx_out[m*3+2] = b * SS + i2;
    w_out[m*3+0] = r0 * inv;
    w_out[m*3+1] = r1 * inv;
    w_out[m*3+2] = r2 * inv;
}

// ---------------------------------------------------------------------------
// fp16 MFMA GEMM, LDS double-buffered with ONE barrier per k-iter.
// C[M x N] = op(A[M x K]) @ W[N x K]^T (+ bias).
// AT = A element type (float or _Float16); OT = C element type.
// Tile 64(M) x 128(N), 4 waves of 32x64, k-chunk 32 (16x16x32 f16 MFMA).
// Optional fused: BN+ReLU on A-stage (fp32 affine); interp gather (f16 P2,
// fp32 accumulate); BN-stats atomics (computed from fp32 pre-rounding).
// ---------------------------------------------------------------------------
template<int K, typename AT, typename OT, bool BN_A, bool FUSE_INTERP, bool FUSE_STATS>
__global__ __launch_bounds__(256, 4) void gemm_mfma_kernel(
    const AT* __restrict__ A, int lda,
    const _Float16* __restrict__ W, int ldw,
    OT* __restrict__ C, int ldc,
    const float* __restrict__ bias,
    const float* __restrict__ scaleA, const float* __restrict__ shiftA,
    const _Float16* __restrict__ P2, const int* __restrict__ idx3, const float* __restrict__ w3,
    float* __restrict__ sumO, float* __restrict__ sqO)
{
    __shared__ _Float16 Ash[2][64 * LPAD];     // 2 x 5 KB
    __shared__ _Float16 Bsh[2][128 * LPAD];    // 2 x 10 KB

    const int tid = threadIdx.x;
    const int m0 = blockIdx.x * 64;
    const int n0 = blockIdx.y * 128;
    const int wave = tid >> 6, lane = tid & 63;
    const int ln = lane & 15, q4 = lane >> 4;
    const int wm = wave & 1, wn = wave >> 1;

    const int ar = tid >> 2, ak = (tid & 3) * 8;   // A staging: 64 rows x 32k
    const int br = tid >> 1, bk = (tid & 1) * 16;  // B staging: 128 rows x 32k

    f32x4 acc[2][4] = {};

    float  avF[8];      // used when AT == float
    f16x8  avH;         // used when AT == _Float16
    f16x8  bvA[2];

    {   // prologue prefetch k0 = 0
        if constexpr (__is_same(AT, float)) {
            const float* ap = A + (size_t)(m0 + ar) * lda + ak;
            *(float4*)&avF[0] = *(const float4*)ap;
            *(float4*)&avF[4] = *(const float4*)(ap + 4);
        } else {
            avH = *(const f16x8*)(A + (size_t)(m0 + ar) * lda + ak);
        }
        const _Float16* bp = W + (size_t)(n0 + br) * ldw + bk;
        bvA[0] = *(const f16x8*)bp;
        bvA[1] = *(const f16x8*)(bp + 8);
    }

    for (int k0 = 0; k0 < K; k0 += 32) {
        const int buf = (k0 >> 5) & 1;

        // ---- transform + store staged regs to LDS[buf] ----
        {
            float av[8];
            if constexpr (__is_same(AT, float)) {
#pragma unroll
                for (int i = 0; i < 8; ++i) av[i] = avF[i];
            } else {
#pragma unroll
                for (int i = 0; i < 8; ++i) av[i] = (float)avH[i];
            }
            if (BN_A) {
#pragma unroll
                for (int i = 0; i < 8; ++i) {
                    float sc = scaleA[k0 + ak + i];
                    float sh = shiftA[k0 + ak + i];
                    av[i] = fmaxf(av[i] * sc + sh, 0.0f);
                }
            }
            f16x8 vh;
#pragma unroll
            for (int i = 0; i < 8; ++i) vh[i] = (_Float16)av[i];
            *(f16x8*)&Ash[buf][ar * LPAD + ak] = vh;
            *(f16x8*)&Bsh[buf][br * LPAD + bk]     = bvA[0];
            *(f16x8*)&Bsh[buf][br * LPAD + bk + 8] = bvA[1];
        }
        __syncthreads();    // single barrier: writers of buf done; dbuf makes it safe

        // ---- issue next chunk's global loads (overlap with MFMA below) ----
        if (k0 + 32 < K) {
            if constexpr (__is_same(AT, float)) {
                const float* ap = A + (size_t)(m0 + ar) * lda + (k0 + 32) + ak;
                *(float4*)&avF[0] = *(const float4*)ap;
                *(float4*)&avF[4] = *(const float4*)(ap + 4);
            } else {
                avH = *(const f16x8*)(A + (size_t)(m0 + ar) * lda + (k0 + 32) + ak);
            }
            const _Float16* bp = W + (size_t)(n0 + br) * ldw + (k0 + 32) + bk;
            bvA[0] = *(const f16x8*)bp;
            bvA[1] = *(const f16x8*)(bp + 8);
        }

        // ---- fragments + MFMA ----
        f16x8 af[2];
#pragma unroll
        for (int mi = 0; mi < 2; ++mi) {
            int arow = wm * 32 + mi * 16 + ln;
            af[mi] = *(const f16x8*)&Ash[buf][arow * LPAD + q4 * 8];
        }
        f16x8 bf[4];
#pragma unroll
        for (int ni = 0; ni < 4; ++ni) {
            int brow = wn * 64 + ni * 16 + ln;
            bf[ni] = *(const f16x8*)&Bsh[buf][brow * LPAD + q4 * 8];
        }
#pragma unroll
        for (int mi = 0; mi < 2; ++mi)
#pragma unroll
            for (int ni = 0; ni < 4; ++ni)
                acc[mi][ni] = __builtin_amdgcn_mfma_f32_16x16x32_f16(af[mi], bf[ni], acc[mi][ni], 0, 0, 0);
    }

    // ---- epilogue ----  C/D layout: col = ln, row = q4*4 + r  (m89/m91)
    if (FUSE_INTERP) {
#pragma unroll
        for (int mi = 0; mi < 2; ++mi) {
#pragma unroll
            for (int r = 0; r < 4; ++r) {
                int row_g = m0 + wm * 32 + mi * 16 + q4 * 4 + r;
                const int*   ip = idx3 + (size_t)row_g * 3;
                const float* wp = w3   + (size_t)row_g * 3;
                int   ia = ip[0], ib = ip[1], ic = ip[2];
                float wa = wp[0], wb = wp[1], wc = wp[2];
#pragma unroll
                for (int ni = 0; ni < 4; ++ni) {
                    int col = n0 + wn * 64 + ni * 16 + ln;
                    acc[mi][ni][r] += wa * (float)P2[(size_t)ia * C1 + col]
                                    + wb * (float)P2[(size_t)ib * C1 + col]
                                    + wc * (float)P2[(size_t)ic * C1 + col];
                }
            }
        }
    }

#pragma unroll
    for (int ni = 0; ni < 4; ++ni) {
        int col = n0 + wn * 64 + ni * 16 + ln;
        float vb = bias ? bias[col] : 0.0f;
        float s = 0.0f, s2 = 0.0f;
#pragma unroll
        for (int mi = 0; mi < 2; ++mi) {
#pragma unroll
            for (int r = 0; r < 4; ++r) {
                int row_g = m0 + wm * 32 + mi * 16 + q4 * 4 + r;
                float v = acc[mi][ni][r] + vb;
                C[(size_t)row_g * ldc + col] = (OT)v;
                s += v; s2 += v * v;
            }
        }
        if (FUSE_STATS) {
            s  += __shfl_xor(s, 16);  s  += __shfl_xor(s, 32);
            s2 += __shfl_xor(s2, 16); s2 += __shfl_xor(s2, 32);
            if (q4 == 0) {
                atomicAdd(&sumO[col], s);
                atomicAdd(&sqO[col], s2);
            }
        }
    }
}

// ---------------------------------------------------------------------------
__global__ void finalize_kernel(
    const float* __restrict__ sum, const float* __restrict__ sumsq,
    const float* __restrict__ g, const float* __restrict__ beta,
    int M, int C, float* __restrict__ scale, float* __restrict__ shift)
{
    int c = threadIdx.x;
    if (c >= C) return;
    float invM = 1.0f / (float)M;
    float mean = sum[c] * invM;
    float var = fmaxf(sumsq[c] * invM - mean * mean, 0.0f);
    float rstd = 1.0f / sqrtf(var + 1e-5f);
    float sc = g[c] * rstd;
    scale[c] = sc;
    shift[c] = beta[c] - mean * sc;
}

__global__ __launch_bounds__(256) void bnrelu_kernel(
    float* __restrict__ X, int total, int C,
    const float* __restrict__ scale, const float* __restrict__ shift)
{
    int i = blockIdx.x * 256 + threadIdx.x;
    if (i >= total) return;
    int c = i & (C - 1);
    X[i] = fmaxf(X[i] * scale[c] + shift[c], 0.0f);
}

// ---------------------------------------------------------------------------
extern "C" void kernel_launch(void* const* d_in, const int* in_sizes, int n_in,
                              void* d_out, int out_size, void* d_ws, size_t ws_size,
                              hipStream_t stream) {
    const float* xyz1    = (const float*)d_in[0];
    const float* xyz2    = (const float*)d_in[1];
    const float* points1 = (const float*)d_in[2];
    const float* points2 = (const float*)d_in[3];
    const float* W1      = (const float*)d_in[4];
    const float* b1      = (const float*)d_in[5];
    const float* g1      = (const float*)d_in[6];
    const float* beta1   = (const float*)d_in[7];
    const float* W2      = (const float*)d_in[8];
    const float* b2      = (const float*)d_in[9];
    const float* g2      = (const float*)d_in[10];
    const float* beta2   = (const float*)d_in[11];
    float* out = (float*)d_out;

    // ws layout (byte offsets, 16B-aligned)
    char* ws = (char*)d_ws;
    size_t off = 0;
    int*   idx = (int*)(ws + off);            off += (size_t)MTOT*3*4;
    float* w   = (float*)(ws + off);          off += (size_t)MTOT*3*4;
    _Float16* P2h = (_Float16*)(ws + off);    off += (size_t)BB*SS*C1*2;    // 8 MB
    _Float16* y1h = (_Float16*)(ws + off);    off += (size_t)MTOT*C1*2;     // 32 MB
    float* stats = (float*)(ws + off);        off += 2048*4;
    float* sum1 = stats;            // 256
    float* sq1  = stats + 256;      // 256
    float* sum2 = stats + 512;      // 128
    float* sq2  = stats + 640;      // 128
    float* scale1 = stats + 768;    // 256
    float* shift1 = stats + 1024;   // 256
    float* scale2 = stats + 1280;   // 128
    float* shift2 = stats + 1408;   // 128
    float4* packed = (float4*)(ws + off);     off += (size_t)BB*SS*16;      // 1 MB
    _Float16* W1c = (_Float16*)(ws + off);    off += (size_t)C1*(D1+D2)*2;
    _Float16* W2c = (_Float16*)(ws + off);    off += (size_t)C2*C1*2;
    // knn partials (12.6 MB) alias the y1h region (y1h written later in stream order)
    float* pdist = (float*)y1h;                              // MTOT*NCH*3 floats
    int*   pidx  = (int*)((char*)y1h + (size_t)MTOT*NCH*3*4);// MTOT*NCH*3 ints

    hipMemsetAsync(stats, 0, 768 * sizeof(float), stream);

    pack_kernel<<<(BB*SS)/256, 256, 0, stream>>>(xyz2, packed);
    wcvt_kernel<<<(C1*(D1+D2))/256, 256, 0, stream>>>(W1, W2, W1c, W2c);

    knn3_partial_kernel<<<BB * (NN/(256*QPT)) * NCH, 256, 0, stream>>>(
        xyz1, packed, pdist, pidx);
    knn3_merge_kernel<<<MTOT/256, 256, 0, stream>>>(pdist, pidx, idx, w);

    // P2 = points2 @ W1[:,128:]^T   [B*S x 256], K=256, f16 out
    gemm_mfma_kernel<256, float, _Float16, false, false, false>
        <<<dim3((BB*SS)/64, C1/128), 256, 0, stream>>>(
        points2, D2, W1c + D1, D1 + D2, P2h, C1,
        nullptr, nullptr, nullptr, nullptr, nullptr, nullptr, nullptr, nullptr);

    // y1 = points1 @ W1[:,:128]^T + b1 + interp;  f16 out; fused BN1 stats (fp32)
    gemm_mfma_kernel<128, float, _Float16, false, true, true>
        <<<dim3(MTOT/64, C1/128), 256, 0, stream>>>(
        points1, D1, W1c, D1 + D2, y1h, C1,
        b1, nullptr, nullptr, P2h, idx, w, sum1, sq1);

    finalize_kernel<<<1, 256, 0, stream>>>(sum1, sq1, g1, beta1, MTOT, C1, scale1, shift1);

    // out = relu(bn1(y1)) @ W2^T + b2;  fp32 out; fused BN2 stats
    gemm_mfma_kernel<256, _Float16, float, true, false, true>
        <<<dim3(MTOT/64, C2/128), 256, 0, stream>>>(
        y1h, C1, W2c, C1, out, C2,
        b2, scale1, shift1, nullptr, nullptr, nullptr, sum2, sq2);

    finalize_kernel<<<1, 128, 0, stream>>>(sum2, sq2, g2, beta2, MTOT, C2, scale2, shift2);
    bnrelu_kernel<<<(MTOT*C2)/256, 256, 0, stream>>>(out, MTOT*C2, C2, scale2, shift2);
}